// Round 1
// baseline (373.075 us; speedup 1.0000x reference)
//
#include <hip/hip_runtime.h>
#include <math.h>

#define BB 256      // batch
#define IC 1152     // in caps
#define OC 10       // out caps
#define OD 16       // out dim
#define ID 8        // in dim
#define ODOC (OC*OD)   // 160

__device__ __forceinline__ float grp16_sum(float x) {
#pragma unroll
    for (int m = 8; m >= 1; m >>= 1) x += __shfl_xor(x, m, 16);
    return x;
}
__device__ __forceinline__ float grp16_max(float x) {
#pragma unroll
    for (int m = 8; m >= 1; m >>= 1) x = fmaxf(x, __shfl_xor(x, m, 16));
    return x;
}
// squash: v = s * sq / ((1+sq)*(sqrt(sq)+1e-8)), sq = sum_d s^2 (16-lane group)
__device__ __forceinline__ float squash_val(float s) {
    float sq = grp16_sum(s * s);
    return s * (sq / ((1.f + sq) * (sqrtf(sq) + 1e-8f)));
}

// Kernel 1: u_hat[b,i,o,d] = sum_k W[i,o,d,k]*u[b,i,k]; also s0raw[b,o,d] += sum_i u_hat.
// block: 256 threads = 16 i_local x 16 d, covers (b, chunk of 16 i's).
// blockIdx: chunk-major so 256 consecutive blocks (different b) share the same W chunk (L2 reuse).
__global__ __launch_bounds__(256) void uhat_kernel(const float* __restrict__ u,
                                                   const float* __restrict__ W,
                                                   float* __restrict__ uhat,
                                                   float* __restrict__ s0) {
    __shared__ float s_sh[ODOC];
    const int t = threadIdx.x;
    if (t < ODOC) s_sh[t] = 0.f;
    __syncthreads();

    const int blk   = blockIdx.x;
    const int b     = blk % BB;
    const int chunk = blk / BB;          // 0..71
    const int i_local = t >> 4;
    const int d       = t & 15;
    const int i = chunk * 16 + i_local;

    const float* up = u + ((size_t)b * IC + i) * ID;
    float uu[ID];
#pragma unroll
    for (int k = 0; k < ID; k++) uu[k] = up[k];

    const float* wp = W + ((size_t)i * OC * OD + d) * ID;   // W[i][o][d][k]
    float* op = uhat + (((size_t)b * IC + i) * OC) * OD + d;

#pragma unroll
    for (int o = 0; o < OC; o++) {
        const float* w8 = wp + (size_t)o * OD * ID;
        float acc = 0.f;
#pragma unroll
        for (int k = 0; k < ID; k++) acc += w8[k] * uu[k];
        op[(size_t)o * OD] = acc;
        atomicAdd(&s_sh[o * OD + d], acc);
    }
    __syncthreads();
    if (t < ODOC) atomicAdd(&s0[b * ODOC + t], s_sh[t]);
}

// Kernel 2: full routing for one b per block. 512 threads = 32 i_local x 16 d.
// Logits L[1152][10] live in LDS for all iterations.
template <bool RECOMP>
__global__ __launch_bounds__(512) void routing_kernel(const float* __restrict__ u,
                                                      const float* __restrict__ W,
                                                      const float* __restrict__ uhat,
                                                      const float* __restrict__ s0,
                                                      float* __restrict__ out) {
    __shared__ float L[IC * OC];      // 46080 B
    __shared__ float v_sh[ODOC];
    __shared__ float s_sh[ODOC];

    const int t = threadIdx.x;
    const int b = blockIdx.x;
    const int i_local = t >> 4;      // 0..31
    const int d       = t & 15;

    for (int idx = t; idx < IC * OC; idx += 512) L[idx] = 0.f;
    if (t < ODOC) s_sh[t] = 0.f;
    __syncthreads();

    const float* ub      = u + (size_t)b * IC * ID;
    const float* uh_base = uhat + (size_t)b * IC * ODOC;

    // ---- v0 from s0 (uniform c = 1/10) ----
    if (!RECOMP) {
        float sv = (t < ODOC) ? s0[b * ODOC + t] * 0.1f : 0.f;
        float vv = squash_val(sv);
        if (t < ODOC) v_sh[t] = vv;
        __syncthreads();
    } else {
        float s_part[OC];
#pragma unroll
        for (int o = 0; o < OC; o++) s_part[o] = 0.f;
        for (int step = 0; step < IC / 32; ++step) {
            const int i = step * 32 + i_local;
            float uu[ID];
            const float* uptr = ub + (size_t)i * ID;
#pragma unroll
            for (int k = 0; k < ID; k++) uu[k] = uptr[k];
            const float* wptr = W + ((size_t)i * OC * OD + d) * ID;
#pragma unroll
            for (int o = 0; o < OC; o++) {
                float acc = 0.f;
#pragma unroll
                for (int k = 0; k < ID; k++) acc += wptr[(size_t)o * OD * ID + k] * uu[k];
                s_part[o] += acc;
            }
        }
#pragma unroll
        for (int o = 0; o < OC; o++) atomicAdd(&s_sh[(o << 4) + d], s_part[o] * 0.1f);
        __syncthreads();
        float sv = (t < ODOC) ? s_sh[t] : 0.f;
        float vv = squash_val(sv);
        __syncthreads();
        if (t < ODOC) { v_sh[t] = vv; s_sh[t] = 0.f; }
        __syncthreads();
    }

    // ---- 2 fused passes: (agreement with v_prev) -> L update -> softmax -> s accum ----
#pragma unroll 1
    for (int pass = 0; pass < 2; ++pass) {
        float s_part[OC];
#pragma unroll
        for (int o = 0; o < OC; o++) s_part[o] = 0.f;

        for (int step = 0; step < IC / 32; ++step) {
            const int i = step * 32 + i_local;
            float uh[OC];
            if (RECOMP) {
                float uu[ID];
                const float* uptr = ub + (size_t)i * ID;
#pragma unroll
                for (int k = 0; k < ID; k++) uu[k] = uptr[k];
                const float* wptr = W + ((size_t)i * OC * OD + d) * ID;
#pragma unroll
                for (int o = 0; o < OC; o++) {
                    float acc = 0.f;
#pragma unroll
                    for (int k = 0; k < ID; k++) acc += wptr[(size_t)o * OD * ID + k] * uu[k];
                    uh[o] = acc;
                }
            } else {
                const float* p = uh_base + (size_t)i * ODOC + d;
#pragma unroll
                for (int o = 0; o < OC; o++) uh[o] = p[(size_t)o * OD];
            }

            // agreement a[o] = sum_d uh[o,d]*v[o,d]; keep a[d] for this lane's o==d
            float a_sel = 0.f;
#pragma unroll
            for (int o = 0; o < OC; o++) {
                float a = grp16_sum(uh[o] * v_sh[o * OD + d]);
                if (d == o) a_sel = a;
            }
            // logit update (lanes d<10 own L[i][d])
            float Lv = 0.f;
            if (d < OC) { Lv = L[i * OC + d] + a_sel; L[i * OC + d] = Lv; }
            // softmax over the 10 o's (held in lanes d=0..9)
            float x  = (d < OC) ? Lv : -3.4e38f;
            float mx = grp16_max(x);
            float e  = (d < OC) ? __expf(x - mx) : 0.f;
            float S  = grp16_sum(e);
            float c_own = e / S;
            // broadcast c[o] and accumulate s
#pragma unroll
            for (int o = 0; o < OC; o++) {
                float c = __shfl(c_own, o, 16);
                s_part[o] += c * uh[o];
            }
        }

#pragma unroll
        for (int o = 0; o < OC; o++) atomicAdd(&s_sh[(o << 4) + d], s_part[o]);
        __syncthreads();

        float sv = (t < ODOC) ? s_sh[t] : 0.f;
        float vv = squash_val(sv);
        if (pass == 0) {
            __syncthreads();
            if (t < ODOC) { v_sh[t] = vv; s_sh[t] = 0.f; }
            __syncthreads();
        } else {
            if (t < ODOC) out[b * ODOC + t] = vv;
        }
    }
}

extern "C" void kernel_launch(void* const* d_in, const int* in_sizes, int n_in,
                              void* d_out, int out_size, void* d_ws, size_t ws_size,
                              hipStream_t stream) {
    const float* u = (const float*)d_in[0];
    const float* W = (const float*)d_in[1];
    float* out = (float*)d_out;

    const size_t uhat_elems = (size_t)BB * IC * OC * OD;            // 47,185,920
    const size_t need = (uhat_elems + (size_t)BB * ODOC) * sizeof(float);

    if (ws_size >= need) {
        float* uhat = (float*)d_ws;
        float* s0   = uhat + uhat_elems;
        hipMemsetAsync(s0, 0, (size_t)BB * ODOC * sizeof(float), stream);
        hipLaunchKernelGGL(uhat_kernel, dim3((IC / 16) * BB), dim3(256), 0, stream,
                           u, W, uhat, s0);
        hipLaunchKernelGGL((routing_kernel<false>), dim3(BB), dim3(512), 0, stream,
                           u, W, uhat, s0, out);
    } else {
        hipLaunchKernelGGL((routing_kernel<true>), dim3(BB), dim3(512), 0, stream,
                           u, W, (const float*)nullptr, (const float*)nullptr, out);
    }
}

// Round 2
// 340.219 us; speedup vs baseline: 1.0966x; 1.0966x over previous
//
#include <hip/hip_runtime.h>
#include <math.h>

#define BB 256      // batch
#define IC 1152     // in caps
#define OC 10       // out caps
#define OD 16       // out dim
#define ID 8        // in dim
#define ODOC (OC*OD)   // 160

// uhat kernel tiling
#define UK_TI 8                 // i per block
#define UK_TB 32                // b per block
#define UK_THREADS 320          // UK_TI * 40 od-quads
#define N_CHUNK (IC/UK_TI)      // 144
#define N_BG (BB/UK_TB)         // 8

__device__ __forceinline__ float grp16_sum(float x) {
#pragma unroll
    for (int m = 8; m >= 1; m >>= 1) x += __shfl_xor(x, m, 16);
    return x;
}
__device__ __forceinline__ float grp16_max(float x) {
#pragma unroll
    for (int m = 8; m >= 1; m >>= 1) x = fmaxf(x, __shfl_xor(x, m, 16));
    return x;
}
// squash over the 16-lane d-group: v = s * sq / ((1+sq)*(sqrt(sq)+1e-8))
__device__ __forceinline__ float squash_val(float s) {
    float sq = grp16_sum(s * s);
    return s * (sq / ((1.f + sq) * (sqrtf(sq) + 1e-8f)));
}

// Kernel 1: uhat[b,i,o,d] = sum_k W[i,o,d,k]*u[b,i,k]; s0[b,o,d] += sum_i uhat.
// Block: 320 threads = 8 i_local x 40 od-quads. W cached in regs (32 f/thread),
// reused across 32 b's. Wave stores are 1KB contiguous float4 streams.
__global__ __launch_bounds__(UK_THREADS) void uhat_kernel(const float* __restrict__ u,
                                                          const float* __restrict__ W,
                                                          float* __restrict__ uhat,
                                                          float* __restrict__ s0) {
    __shared__ float us[UK_TB][UK_TI][ID];     // 8 KB
    __shared__ float s0_blk[UK_TB][ODOC];      // 20 KB

    const int t = threadIdx.x;
    const int chunk = blockIdx.x % N_CHUNK;
    const int bg    = blockIdx.x / N_CHUNK;
    const int i0 = chunk * UK_TI;
    const int b0 = bg * UK_TB;

    for (int idx = t; idx < UK_TB * ODOC; idx += UK_THREADS)
        ((float*)s0_blk)[idx] = 0.f;
    for (int idx = t; idx < UK_TB * UK_TI * ID; idx += UK_THREADS) {
        int bb = idx / (UK_TI * ID), r = idx % (UK_TI * ID);
        int i = r / ID, k = r % ID;
        us[bb][i][k] = u[((size_t)(b0 + bb) * IC + (i0 + i)) * ID + k];
    }
    __syncthreads();

    const int i_local = t / 40;
    const int r  = t % 40;
    const int o  = r >> 2;
    const int dq = r & 3;
    const int i  = i0 + i_local;

    // W rows d = dq*4 .. dq*4+3, 8 k each -> 32 regs, reused for all 32 b's
    float w[4][ID];
    const float* wp = W + (((size_t)i * OC + o) * OD + dq * 4) * ID;
#pragma unroll
    for (int j = 0; j < 4; j++)
#pragma unroll
        for (int k = 0; k < ID; k++) w[j][k] = wp[j * ID + k];

    for (int bb = 0; bb < UK_TB; bb++) {
        const int bi = (bb + blockIdx.x) & (UK_TB - 1);   // stagger b across blocks
        const int b  = b0 + bi;
        float uu[ID];
#pragma unroll
        for (int k = 0; k < ID; k++) uu[k] = us[bi][i_local][k];
        float a0 = 0.f, a1 = 0.f, a2 = 0.f, a3 = 0.f;
#pragma unroll
        for (int k = 0; k < ID; k++) {
            a0 += w[0][k] * uu[k];
            a1 += w[1][k] * uu[k];
            a2 += w[2][k] * uu[k];
            a3 += w[3][k] * uu[k];
        }
        float4 acc = make_float4(a0, a1, a2, a3);
        *(float4*)(uhat + ((size_t)b * IC + i) * ODOC + o * OD + dq * 4) = acc;
        atomicAdd(&s0_blk[bi][o * OD + dq * 4 + 0], a0);
        atomicAdd(&s0_blk[bi][o * OD + dq * 4 + 1], a1);
        atomicAdd(&s0_blk[bi][o * OD + dq * 4 + 2], a2);
        atomicAdd(&s0_blk[bi][o * OD + dq * 4 + 3], a3);
    }
    __syncthreads();
    for (int idx = t; idx < UK_TB * ODOC; idx += UK_THREADS) {
        int bi = idx / ODOC, od = idx % ODOC;
        atomicAdd(&s0[(size_t)(b0 + bi) * ODOC + od], s0_blk[bi][od]);
    }
}

// Kernel 2: routing for one b per block. 512 threads = 32 i-lanes x 16 slots
// (slot = o for slot<10). Lane owns the uh[o,:] row: agreement dot and s
// accumulation are thread-local; softmax is an 8-shfl 16-lane op; L slot is
// lane-owned in LDS. No barriers inside the step loop -> loads pipeline.
__global__ __launch_bounds__(512) void routing_kernel(const float* __restrict__ uhat,
                                                      const float* __restrict__ s0,
                                                      float* __restrict__ out) {
    __shared__ float L[IC * OC];       // 46080 B
    __shared__ float v_sh[ODOC];
    __shared__ float red[32 * ODOC];   // 20480 B

    const int t = threadIdx.x;
    const int b = blockIdx.x;
    const int il   = t >> 4;           // 0..31
    const int slot = t & 15;
    const bool act = slot < OC;

    for (int idx = t; idx < IC * OC; idx += 512) L[idx] = 0.f;

    // v0 = squash(0.1 * s0[b])
    float sv0 = (t < ODOC) ? s0[(size_t)b * ODOC + t] * 0.1f : 0.f;
    float vv0 = squash_val(sv0);
    if (t < ODOC) v_sh[t] = vv0;
    __syncthreads();

    const float* ub = uhat + (size_t)b * IC * ODOC;

#pragma unroll 1
    for (int pass = 0; pass < 2; pass++) {
        float vr[OD];
        if (act) {
#pragma unroll
            for (int q = 0; q < 4; q++) {
                float4 vq = *(const float4*)&v_sh[slot * OD + q * 4];
                vr[q * 4 + 0] = vq.x; vr[q * 4 + 1] = vq.y;
                vr[q * 4 + 2] = vq.z; vr[q * 4 + 3] = vq.w;
            }
        }
        float sp[OD];
#pragma unroll
        for (int d = 0; d < OD; d++) sp[d] = 0.f;

        for (int step = 0; step < IC / 32; step++) {
            const int i = step * 32 + il;
            float uh[OD];
            float a = 0.f;
            if (act) {
                const float4* p = (const float4*)(ub + (size_t)i * ODOC + slot * OD);
#pragma unroll
                for (int q = 0; q < 4; q++) {
                    float4 x = p[q];
                    uh[q * 4 + 0] = x.x; uh[q * 4 + 1] = x.y;
                    uh[q * 4 + 2] = x.z; uh[q * 4 + 3] = x.w;
                }
#pragma unroll
                for (int d = 0; d < OD; d++) a += uh[d] * vr[d];
            }
            float Lv = -3.4e38f;
            if (act) { Lv = L[i * OC + slot] + a; L[i * OC + slot] = Lv; }
            float mx = grp16_max(Lv);
            float e  = act ? __expf(Lv - mx) : 0.f;
            float S  = grp16_sum(e);
            float c  = e / S;
            if (act) {
#pragma unroll
                for (int d = 0; d < OD; d++) sp[d] += c * uh[d];
            }
        }

        // reduce sp over the 32 i-lanes
        if (act) {
#pragma unroll
            for (int q = 0; q < 4; q++)
                *(float4*)&red[il * ODOC + slot * OD + q * 4] =
                    make_float4(sp[q * 4], sp[q * 4 + 1], sp[q * 4 + 2], sp[q * 4 + 3]);
        }
        __syncthreads();
        float snew = 0.f;
        if (t < ODOC) {
#pragma unroll 8
            for (int j = 0; j < 32; j++) snew += red[j * ODOC + t];
        }
        float vnew = squash_val(snew);
        __syncthreads();
        if (pass == 0) {
            if (t < ODOC) v_sh[t] = vnew;
            __syncthreads();
        } else {
            if (t < ODOC) out[(size_t)b * ODOC + t] = vnew;
        }
    }
}

extern "C" void kernel_launch(void* const* d_in, const int* in_sizes, int n_in,
                              void* d_out, int out_size, void* d_ws, size_t ws_size,
                              hipStream_t stream) {
    const float* u = (const float*)d_in[0];
    const float* W = (const float*)d_in[1];
    float* out = (float*)d_out;

    const size_t uhat_elems = (size_t)BB * IC * ODOC;   // 47,185,920
    float* uhat = (float*)d_ws;
    float* s0   = uhat + uhat_elems;

    hipMemsetAsync(s0, 0, (size_t)BB * ODOC * sizeof(float), stream);
    hipLaunchKernelGGL(uhat_kernel, dim3(N_CHUNK * N_BG), dim3(UK_THREADS), 0, stream,
                       u, W, uhat, s0);
    hipLaunchKernelGGL(routing_kernel, dim3(BB), dim3(512), 0, stream,
                       uhat, s0, out);
}

// Round 3
// 103.828 us; speedup vs baseline: 3.5932x; 3.2767x over previous
//
#include <hip/hip_runtime.h>
#include <math.h>

#define BB 256      // batch
#define IC 1152     // in caps
#define OC 10       // out caps
#define OD 16       // out dim
#define ID 8        // in dim
#define ODOC (OC*OD)   // 160

#define NCHUNK (IC/8)   // 144
#define NBG 8
#define UK_THREADS 320

typedef unsigned int   u32;
typedef unsigned short u16;

__device__ __forceinline__ float grp16_sum(float x) {
#pragma unroll
    for (int m = 8; m >= 1; m >>= 1) x += __shfl_xor(x, m, 16);
    return x;
}
__device__ __forceinline__ float grp16_max(float x) {
#pragma unroll
    for (int m = 8; m >= 1; m >>= 1) x = fmaxf(x, __shfl_xor(x, m, 16));
    return x;
}
__device__ __forceinline__ float squash_val(float s) {
    float sq = grp16_sum(s * s);
    return s * (sq / ((1.f + sq) * (sqrtf(sq) + 1e-8f)));
}

__device__ __forceinline__ u32 bf16_rne(float f) {
    u32 x = __float_as_uint(f);
    return (x + 0x7FFFu + ((x >> 16) & 1u)) >> 16;
}
__device__ __forceinline__ u32 pack_bf16x2(float lo, float hi) {
    return bf16_rne(lo) | (bf16_rne(hi) << 16);
}
__device__ __forceinline__ float bf_lo(u32 v) { return __uint_as_float(v << 16); }
__device__ __forceinline__ float bf_hi(u32 v) { return __uint_as_float(v & 0xFFFF0000u); }

// Kernel 1: uhat[b,i,o,d] (bf16) = W[i,o,:,:] @ u[b,i,:].
// Block = (chunk of 8 i's) x (b residue class bg). Thread = (i_local, o, dq).
// W cached in regs (32 f/thread, reused over 32 b's). At loop iter bb ALL
// blocks write b = 8*bb + bg: the grid's instantaneous write footprint is
// 8 complete contiguous b-rows (2.5 MB dense, monotonically advancing).
// Per block per iter: 8 adjacent i-rows x 320 B = 2560 B contiguous.
__global__ __launch_bounds__(UK_THREADS) void uhat_kernel(const float* __restrict__ u,
                                                          const float* __restrict__ W,
                                                          u16* __restrict__ uhat) {
    __shared__ float us[32][8][ID];   // 8 KB

    const int t = threadIdx.x;
    const int chunk = blockIdx.x % NCHUNK;
    const int bg    = blockIdx.x / NCHUNK;    // 0..7
    const int i0 = chunk * 8;

    for (int idx = t; idx < 32 * 8 * ID; idx += UK_THREADS) {
        int bb = idx >> 6, r = idx & 63, il = r >> 3, k = r & 7;
        us[bb][il][k] = u[((size_t)(bb * NBG + bg) * IC + (i0 + il)) * ID + k];
    }
    __syncthreads();

    const int il = t / 40;
    const int r  = t % 40;
    const int o  = r >> 2;
    const int dq = r & 3;
    const int i  = i0 + il;

    float w[4][ID];
    const float* wp = W + (((size_t)i * OC + o) * OD + dq * 4) * ID;
#pragma unroll
    for (int j = 0; j < 4; j++)
#pragma unroll
        for (int k = 0; k < ID; k++) w[j][k] = wp[j * ID + k];

    for (int bb = 0; bb < 32; ++bb) {
        const int b = bb * NBG + bg;
        float a0 = 0.f, a1 = 0.f, a2 = 0.f, a3 = 0.f;
#pragma unroll
        for (int k = 0; k < ID; k++) {
            float uu = us[bb][il][k];
            a0 += w[0][k] * uu;
            a1 += w[1][k] * uu;
            a2 += w[2][k] * uu;
            a3 += w[3][k] * uu;
        }
        uint2 pk = make_uint2(pack_bf16x2(a0, a1), pack_bf16x2(a2, a3));
        *(uint2*)(uhat + ((size_t)b * IC + i) * ODOC + o * OD + dq * 4) = pk;
    }
}

// Kernel 2: routing for one b per block. 512 threads = 32 i-lanes x 16 slots
// (slot = o for slot < 10). Pass 0 computes s0 (uniform c) from uhat; passes
// 1-2 fuse agreement -> logit -> softmax -> s-accum. Logits live in REGISTERS
// (lane owns L[i][slot] for its 36 i's; step loops fully unrolled so indexing
// is static). No LDS ops and no barriers inside the step loops.
__global__ __launch_bounds__(512) void routing_kernel(const u16* __restrict__ uhat,
                                                      float* __restrict__ out) {
    __shared__ float v_sh[ODOC];
    __shared__ float red[32 * ODOC];   // 20 KB

    const int t = threadIdx.x;
    const int b = blockIdx.x;
    const int il   = t >> 4;           // 0..31
    const int slot = t & 15;
    const bool act = slot < OC;

    const u16* ub = uhat + (size_t)b * IC * ODOC;

    float Lreg[36];
#pragma unroll
    for (int j = 0; j < 36; ++j) Lreg[j] = 0.f;

    float sp[OD];
#pragma unroll
    for (int d = 0; d < OD; ++d) sp[d] = 0.f;

    // ---- pass 0: s0 = 0.1 * sum_i uh ----
#pragma unroll
    for (int step = 0; step < 36; ++step) {
        if (act) {
            const uint4* p = (const uint4*)(ub + (size_t)(step * 32 + il) * ODOC + slot * OD);
            uint4 A = p[0], B = p[1];
            sp[0]  += bf_lo(A.x); sp[1]  += bf_hi(A.x);
            sp[2]  += bf_lo(A.y); sp[3]  += bf_hi(A.y);
            sp[4]  += bf_lo(A.z); sp[5]  += bf_hi(A.z);
            sp[6]  += bf_lo(A.w); sp[7]  += bf_hi(A.w);
            sp[8]  += bf_lo(B.x); sp[9]  += bf_hi(B.x);
            sp[10] += bf_lo(B.y); sp[11] += bf_hi(B.y);
            sp[12] += bf_lo(B.z); sp[13] += bf_hi(B.z);
            sp[14] += bf_lo(B.w); sp[15] += bf_hi(B.w);
        }
    }
    if (act) {
#pragma unroll
        for (int q = 0; q < 4; q++)
            *(float4*)&red[il * ODOC + slot * OD + q * 4] =
                make_float4(sp[q * 4], sp[q * 4 + 1], sp[q * 4 + 2], sp[q * 4 + 3]);
    }
    __syncthreads();
    {
        float s0v = 0.f;
        if (t < ODOC) {
#pragma unroll 8
            for (int j = 0; j < 32; j++) s0v += red[j * ODOC + t];
            s0v *= 0.1f;
        }
        float v0 = squash_val(s0v);
        __syncthreads();
        if (t < ODOC) v_sh[t] = v0;
        __syncthreads();
    }

    // ---- passes 1-2 ----
#pragma unroll 1
    for (int pass = 1; pass <= 2; ++pass) {
        float vr[OD];
        if (act) {
#pragma unroll
            for (int q = 0; q < 4; q++) {
                float4 vq = *(const float4*)&v_sh[slot * OD + q * 4];
                vr[q * 4 + 0] = vq.x; vr[q * 4 + 1] = vq.y;
                vr[q * 4 + 2] = vq.z; vr[q * 4 + 3] = vq.w;
            }
        }
#pragma unroll
        for (int d = 0; d < OD; ++d) sp[d] = 0.f;

#pragma unroll
        for (int step = 0; step < 36; ++step) {
            float uh[OD];
            float a = 0.f;
            if (act) {
                const uint4* p = (const uint4*)(ub + (size_t)(step * 32 + il) * ODOC + slot * OD);
                uint4 A = p[0], B = p[1];
                uh[0]  = bf_lo(A.x); uh[1]  = bf_hi(A.x);
                uh[2]  = bf_lo(A.y); uh[3]  = bf_hi(A.y);
                uh[4]  = bf_lo(A.z); uh[5]  = bf_hi(A.z);
                uh[6]  = bf_lo(A.w); uh[7]  = bf_hi(A.w);
                uh[8]  = bf_lo(B.x); uh[9]  = bf_hi(B.x);
                uh[10] = bf_lo(B.y); uh[11] = bf_hi(B.y);
                uh[12] = bf_lo(B.z); uh[13] = bf_hi(B.z);
                uh[14] = bf_lo(B.w); uh[15] = bf_hi(B.w);
#pragma unroll
                for (int d = 0; d < OD; d++) a += uh[d] * vr[d];
            }
            float Lv = -3.4e38f;
            if (act) { Lreg[step] += a; Lv = Lreg[step]; }
            float mx = grp16_max(Lv);
            float e  = act ? __expf(Lv - mx) : 0.f;
            float S  = grp16_sum(e);
            float c  = e / S;
            if (act) {
#pragma unroll
                for (int d = 0; d < OD; d++) sp[d] += c * uh[d];
            }
        }

        if (act) {
#pragma unroll
            for (int q = 0; q < 4; q++)
                *(float4*)&red[il * ODOC + slot * OD + q * 4] =
                    make_float4(sp[q * 4], sp[q * 4 + 1], sp[q * 4 + 2], sp[q * 4 + 3]);
        }
        __syncthreads();
        float sn = 0.f;
        if (t < ODOC) {
#pragma unroll 8
            for (int j = 0; j < 32; j++) sn += red[j * ODOC + t];
        }
        float vn = squash_val(sn);
        __syncthreads();
        if (pass == 1) {
            if (t < ODOC) v_sh[t] = vn;
            __syncthreads();
        } else {
            if (t < ODOC) out[(size_t)b * ODOC + t] = vn;
        }
    }
}

extern "C" void kernel_launch(void* const* d_in, const int* in_sizes, int n_in,
                              void* d_out, int out_size, void* d_ws, size_t ws_size,
                              hipStream_t stream) {
    const float* u = (const float*)d_in[0];
    const float* W = (const float*)d_in[1];
    float* out = (float*)d_out;

    u16* uhat = (u16*)d_ws;   // 256*1152*160 bf16 = 94.4 MB

    hipLaunchKernelGGL(uhat_kernel, dim3(NCHUNK * NBG), dim3(UK_THREADS), 0, stream,
                       u, W, uhat);
    hipLaunchKernelGGL(routing_kernel, dim3(BB), dim3(512), 0, stream,
                       uhat, out);
}